// Round 6
// baseline (192.065 us; speedup 1.0000x reference)
//
#include <hip/hip_runtime.h>
#include <math.h>

#define BSZ 2
#define TSEQ 2048
#define CDIM 1024
#define HNUM 16

typedef __attribute__((ext_vector_type(8))) short bhalf8;
typedef __attribute__((ext_vector_type(4))) short bhalf4;
typedef __attribute__((ext_vector_type(4))) float floatx4;

__device__ __forceinline__ unsigned short f2bf(float f) {
    union { float f; unsigned u; } v;
    v.f = f;
    unsigned r = v.u + 0x7FFFu + ((v.u >> 16) & 1u);
    return (unsigned short)(r >> 16);
}

__device__ __forceinline__ floatx4 fx4_zero() { floatx4 z = {0.f,0.f,0.f,0.f}; return z; }

// async global->LDS, 16 B per lane. lds dest = (wave-uniform base) + lane*16.
typedef __attribute__((address_space(3))) unsigned int lds_u32;
typedef const __attribute__((address_space(1))) unsigned int g_u32;
__device__ __forceinline__ void async_copy16(const void* g, void* l) {
    __builtin_amdgcn_global_load_lds((g_u32*)g, (lds_u32*)l, 16, 0, 0);
}

// ---------------------------------------------------------------------------
// Merged prepass (one launch):
//  blocks [0,2048):    x fp32 -> xb bf16 (8 elems/thread)
//  blocks [2048,5120): W_attn [1024,3072] -> WtA [3072,1024] bf16 transpose
//  blocks [5120,6144): W_proj [1024,1024] -> WtP [1024,1024] bf16 transpose
// ---------------------------------------------------------------------------
__device__ __forceinline__ void trans_tile(
    const float* __restrict__ W, unsigned short* __restrict__ Wt,
    int K, int N, int n0, int k0, int tid, float (*t)[33])
{
    const int tx = tid & 31, ty = tid >> 5;
#pragma unroll
    for (int i = 0; i < 4; ++i)
        t[ty + i * 8][tx] = W[(size_t)(k0 + ty + i * 8) * N + n0 + tx];
    __syncthreads();
#pragma unroll
    for (int i = 0; i < 4; ++i)
        Wt[(size_t)(n0 + ty + i * 8) * K + k0 + tx] = f2bf(t[tx][ty + i * 8]);
}

__global__ __launch_bounds__(256) void prepass(
    const float* __restrict__ x, unsigned short* __restrict__ xb,
    const float* __restrict__ Wa, unsigned short* __restrict__ WtA,
    const float* __restrict__ Wp, unsigned short* __restrict__ WtP)
{
    __shared__ float t[32][33];
    const int bid = blockIdx.x;
    const int tid = threadIdx.x;
    if (bid < 2048) {
        size_t i = ((size_t)bid * 256 + tid) * 8;
        float4 a = *(const float4*)(x + i);
        float4 b = *(const float4*)(x + i + 4);
        uint4 o;
        o.x = (unsigned)f2bf(a.x) | ((unsigned)f2bf(a.y) << 16);
        o.y = (unsigned)f2bf(a.z) | ((unsigned)f2bf(a.w) << 16);
        o.z = (unsigned)f2bf(b.x) | ((unsigned)f2bf(b.y) << 16);
        o.w = (unsigned)f2bf(b.z) | ((unsigned)f2bf(b.w) << 16);
        *(uint4*)(xb + i) = o;
    } else if (bid < 5120) {
        int tl = bid - 2048;                       // 96 n-tiles x 32 k-tiles
        trans_tile(Wa, WtA, 1024, 3072, (tl % 96) * 32, (tl / 96) * 32, tid, t);
    } else {
        int tl = bid - 5120;                       // 32 x 32
        trans_tile(Wp, WtP, 1024, 1024, (tl % 32) * 32, (tl / 32) * 32, tid, t);
    }
}

// ---------------------------------------------------------------------------
// bf16 MFMA GEMM (B^T input) + bias, single-barrier double-buffered K-loop.
// C[M,N] = A[M,K] @ Bt[N,K]^T + bias[N].  Block tile BM x BN, BK=32,
// 256 threads (4 waves). Wave covers (BM/2)x(BN/2); acc = MTxNT of 16x16.
// LDS chunk swizzle (T2): data (row r, k-chunk q) lives at slot
// c = (q + (r>>1)) & 3 of row r; staged via pre-swizzled GLOBAL source,
// read back with sw8 = ((quad + (col16>>1)) & 3) * 8 (conflict-free).
// Blocks whose colbase >= v_start write TRANSPOSED to vt via ushort4.
// Columns < q_end get scaled by 0.125*log2(e) in fp32 before bf16 round.
// ---------------------------------------------------------------------------
template<int BM, int BN, bool OUT_BF16>
__global__ __launch_bounds__(256) void gemm_bt(
    const unsigned short* __restrict__ A, const unsigned short* __restrict__ Bt,
    const float* __restrict__ bias, void* __restrict__ Cp,
    int M, int N, int K, int v_start, unsigned short* __restrict__ vt, int q_end)
{
    constexpr int ALINES = BM / 64;
    constexpr int BLINES = BN / 64;
    constexpr int MT = BM / 32;
    constexpr int NT = BN / 32;
    __shared__ unsigned short As[2][BM * 32];
    __shared__ unsigned short Bs[2][BN * 32];

    const int tid   = threadIdx.x;
    const int bm    = blockIdx.y;
    const int bn    = blockIdx.x;
    const int wave  = tid >> 6;
    const int col16 = tid & 15;
    const int quad  = (tid & 63) >> 4;
    const int wm    = (wave >> 1) * (BM / 2);
    const int wn    = (wave & 1) * (BN / 2);

    floatx4 acc[MT][NT];
#pragma unroll
    for (int i = 0; i < MT; ++i)
#pragma unroll
        for (int j = 0; j < NT; ++j) acc[i][j] = fx4_zero();

    // staging: lane covers row gr, global k-chunk pre-swizzled so that LDS
    // slot (gr, tid&3) holds chunk ((tid&3) - (gr>>1)) & 3
    const int gr = tid >> 2;
    const int gk = (((tid & 3) + 4 - ((tid >> 3) & 3)) & 3) * 8;
    const unsigned short* Ab = A  + (size_t)(bm * BM + gr) * K + gk;
    const unsigned short* Bb = Bt + (size_t)(bn * BN + gr) * K + gk;

    // fragment read: slot of k-chunk `quad` for row (.. + col16)
    const int sw8 = ((quad + (col16 >> 1)) & 3) * 8;

#define STAGE(k0, bf) { \
    char* AsB = (char*)As[bf] + wave * 1024; \
    char* BsB = (char*)Bs[bf] + wave * 1024; \
    _Pragma("unroll") \
    for (int l = 0; l < ALINES; ++l) \
        async_copy16(Ab + (size_t)l * 64 * K + (k0), AsB + l * 4096); \
    _Pragma("unroll") \
    for (int l = 0; l < BLINES; ++l) \
        async_copy16(Bb + (size_t)l * 64 * K + (k0), BsB + l * 4096); }

#define COMPUTE(bf) { \
    bhalf8 a[MT], b[NT]; \
    _Pragma("unroll") \
    for (int i = 0; i < MT; ++i) \
        a[i] = *(const bhalf8*)&As[bf][(wm + i * 16 + col16) * 32 + sw8]; \
    _Pragma("unroll") \
    for (int j = 0; j < NT; ++j) \
        b[j] = *(const bhalf8*)&Bs[bf][(wn + j * 16 + col16) * 32 + sw8]; \
    _Pragma("unroll") \
    for (int i = 0; i < MT; ++i) \
        _Pragma("unroll") \
        for (int j = 0; j < NT; ++j) \
            acc[i][j] = __builtin_amdgcn_mfma_f32_16x16x32_bf16(a[i], b[j], acc[i][j], 0, 0, 0); }

    STAGE(0, 0);
    __syncthreads();
    int buf = 0;
    for (int k0 = 0; k0 < K - 32; k0 += 32) {
        STAGE(k0 + 32, buf ^ 1);
        COMPUTE(buf);
        __syncthreads();
        buf ^= 1;
    }
    COMPUTE(buf);
#undef STAGE
#undef COMPUTE

    const int colbase = bn * BN + wn;
    const bool vpath = (v_start >= 0) && (colbase >= v_start);  // wave-uniform
    const float csc = (colbase < q_end) ? 0.18033688f : 1.0f;   // wave-uniform
#pragma unroll
    for (int j = 0; j < NT; ++j) {
        int col = colbase + j * 16 + col16;
        float bv = bias[col];
#pragma unroll
        for (int i = 0; i < MT; ++i) {
            if (vpath) {
                int row0 = bm * BM + wm + i * 16 + quad * 4;
                ushort4 o;
                o.x = f2bf((acc[i][j][0] + bv) * csc);
                o.y = f2bf((acc[i][j][1] + bv) * csc);
                o.z = f2bf((acc[i][j][2] + bv) * csc);
                o.w = f2bf((acc[i][j][3] + bv) * csc);
                size_t vrow = (size_t)((row0 >> 11) * 1024 + (col - v_start));
                *(ushort4*)(vt + vrow * 2048 + (row0 & 2047)) = o;
            } else {
#pragma unroll
                for (int r = 0; r < 4; ++r) {
                    int row = bm * BM + wm + i * 16 + quad * 4 + r;
                    float v = (acc[i][j][r] + bv) * csc;
                    if (OUT_BF16)
                        ((unsigned short*)Cp)[(size_t)row * N + col] = f2bf(v);
                    else
                        ((float*)Cp)[(size_t)row * N + col] = v;
                }
            }
        }
    }
}

// ---------------------------------------------------------------------------
// MFMA flash attention v8: QBLK=128, 8 waves (512 thr), 2 blocks/CU.
// Rationale (r5 post-mortem): v6b was barrier-count bound (~1650 cy/tile
// vs ~300 cy pipe work). Each K/V tile now serves 128 q-rows -> tile-barrier
// events per (b,h) drop 528->272, worst-CU critical path 80->48 tiles, and
// per-wave staging halves (1 gload_lds + 1 V-load per lane, was 2+2).
// Per-wave per-tile compute stream is IDENTICAL to v6b (bit-identical math
// per q-row). Causality: wave w diag tile = 2qb + (w>>2); in-loop tiles are
// FULL (kb<wdiag) or DIAG (kb==wdiag); extra final tile kb=2qb+1 is DIAG for
// waves 4-7, skipped by waves 0-3 (all wave-uniform branches).
// K image (unchanged form): row*128B + (chunk^(row&7))*16B, gload_lds.
// V image NEW: stride 64 + 16B-chunk XOR swizzle: slot = chunk ^ (row&7),
// applied on the reg-staged ds_write AND the PV read (2-way max = free).
// LDS = 16KB K + 16KB V = 32768 B.
// ---------------------------------------------------------------------------
template<bool DIAG>
__device__ __forceinline__ void attn_tile(
    const unsigned short* __restrict__ Ks, const unsigned short* __restrict__ Vt,
    const bhalf8* qf, floatx4* oT, floatx4& accl,
    int col16, int quad, int qloc)
{
    const int sx = col16 & 7;
    const int qh = quad >> 1, ql = (quad & 1) * 4;
    const floatx4 minusC = {-17.31234049f, -17.31234049f, -17.31234049f, -17.31234049f};
    const bhalf4 ones = {0x3F80, 0x3F80, 0x3F80, 0x3F80};   // bf16 1.0 x4

    floatx4 s[4];
#pragma unroll
    for (int n = 0; n < 4; ++n) {
        const int row = 16 * n + col16;
        bhalf8 k0 = *(const bhalf8*)&Ks[row * 64 + ((quad ^ sx) * 8)];
        bhalf8 k1 = *(const bhalf8*)&Ks[row * 64 + (((4 + quad) ^ sx) * 8)];
        floatx4 t = __builtin_amdgcn_mfma_f32_16x16x32_bf16(k0, qf[0], minusC, 0, 0, 0);
        s[n] = __builtin_amdgcn_mfma_f32_16x16x32_bf16(k1, qf[1], t, 0, 0, 0);
    }

    bhalf4 pb[4];
#pragma unroll
    for (int n = 0; n < 4; ++n) {
        unsigned a[4];
#pragma unroll
        for (int r = 0; r < 4; ++r) {
            float p = exp2f(s[n][r]);
            if (DIAG) {
                if (16 * n + quad * 4 + r > qloc) p = 0.f;
            }
            a[r] = __float_as_uint(p) + 0x8000u;   // bias-round to bf16
        }
        union { unsigned u[2]; bhalf4 b; } uu;
        uu.u[0] = (a[0] >> 16) | (a[1] & 0xffff0000u);
        uu.u[1] = (a[2] >> 16) | (a[3] & 0xffff0000u);
        pb[n] = uu.b;
        // l-partial on the MFMA pipe: C[*][q] += sum_k P^T[k][q]
        accl = __builtin_amdgcn_mfma_f32_16x16x16bf16_1k(ones, pb[n], accl, 0, 0, 0);
    }

#pragma unroll
    for (int n = 0; n < 4; ++n) {
#pragma unroll
        for (int dt = 0; dt < 4; ++dt) {
            // V read with chunk-XOR deswizzle: row d, wanted chunk (2n+qh)
            const int idx = (16 * dt + col16) * 64 + (((2 * n + qh) ^ sx) << 3) + ql;
            const bhalf4 av = *(const bhalf4*)&Vt[idx];
            oT[dt] = __builtin_amdgcn_mfma_f32_16x16x16bf16_1k(av, pb[n], oT[dt], 0, 0, 0);
        }
    }
}

__global__ __launch_bounds__(512) void attn_mfma(
    const unsigned short* __restrict__ qkv,
    const unsigned short* __restrict__ vT,
    unsigned short* __restrict__ yout)
{
    __shared__ unsigned short Kbuf[2][64 * 64];
    __shared__ unsigned short Vbuf[2][64 * 64];

    const int tid   = threadIdx.x;
    const int wave  = tid >> 6;                               // 0..7
    const int col16 = tid & 15;
    const int quad  = (tid & 63) >> 4;
    const int qb    = (int)gridDim.y - 1 - (int)blockIdx.y;   // 0..15, longest first
    const int bh    = blockIdx.x;
    const int b     = bh >> 4;
    const int h     = bh & 15;

    const unsigned short* base  = qkv + (size_t)b * TSEQ * 3072 + h * 64;
    const unsigned short* kbase = base + CDIM;
    const unsigned short* vtb   = vT + (size_t)(b * 1024 + h * 64) * 2048;

    // Q fragments: lane holds Q[q=qb*128+wave*16+col16][d=quad*8+j]
    bhalf8 qf[2];
    {
        const unsigned short* qrow =
            base + (size_t)(qb * 128 + wave * 16 + col16) * 3072 + quad * 8;
        qf[0] = *(const bhalf8*)qrow;
        qf[1] = *(const bhalf8*)(qrow + 32);
    }

    // K staging: 512 lanes cover rows 0..63 (tid>>3), chunk (tid&7)^(row&7);
    // dest = Kbuf + wave*1024 + lane*16 reproduces exactly that (row,slot) map
    const int krow = tid >> 3;
    const int kchk = (tid & 7) ^ (krow & 7);
    const unsigned short* ksrc = kbase + (size_t)krow * 3072 + kchk * 8;

    // V staging: lane covers vT row d=tid>>3, global t-chunk tid&7;
    // LDS slot = (chunk ^ (d&7)) within row d (16B granules)
    const int vd  = tid >> 3;
    const int vt0 = (tid & 7) * 8;
    const int vsl = vd * 64 + (((tid & 7) ^ (vd & 7)) * 8);
    const unsigned short* vsrc = vtb + (size_t)vd * 2048 + vt0;

#define KSTAGE(kb, bf) \
    async_copy16(ksrc + (size_t)(kb) * 64 * 3072, (char*)Kbuf[bf] + wave * 1024);

    floatx4 oT[4];
#pragma unroll
    for (int dt = 0; dt < 4; ++dt) oT[dt] = fx4_zero();
    floatx4 accl = fx4_zero();
    const int qloc  = (wave & 3) * 16 + col16;   // q row within its 64-row half
    const int wdiag = 2 * qb + (wave >> 2);      // this wave's diagonal tile

    {   // prologue: stage tile 0 into buf 0
        uint4 nv = *(const uint4*)vsrc;
        KSTAGE(0, 0);
        *(uint4*)&Vbuf[0][vsl] = nv;
    }
    __syncthreads();
    int buf = 0;
    const int last = 2 * qb + 1;
    for (int kb = 0; kb < last; ++kb) {
        uint4 nv = *(const uint4*)(vsrc + (size_t)(kb + 1) * 64);
        KSTAGE(kb + 1, buf ^ 1);
        if (kb < wdiag)
            attn_tile<false>(Kbuf[buf], Vbuf[buf], qf, oT, accl, col16, quad, qloc);
        else  // kb == wdiag (only waves 0-3 reach this in-loop)
            attn_tile<true>(Kbuf[buf], Vbuf[buf], qf, oT, accl, col16, quad, qloc);
        *(uint4*)&Vbuf[buf ^ 1][vsl] = nv;
        __syncthreads();
        buf ^= 1;
    }
    // final tile kb=last: DIAG for waves 4-7, skipped by waves 0-3
    if (wdiag == last)
        attn_tile<true>(Kbuf[buf], Vbuf[buf], qf, oT, accl, col16, quad, qloc);
#undef KSTAGE

    // epilogue: every lane holds the full l for its q; O^T/l, store
    const float inv = 1.0f / accl[0];
    const size_t row = (size_t)b * TSEQ + (size_t)qb * 128 + wave * 16 + col16;
#pragma unroll
    for (int dt = 0; dt < 4; ++dt) {
        ushort4 o;
        o.x = f2bf(oT[dt][0] * inv);
        o.y = f2bf(oT[dt][1] * inv);
        o.z = f2bf(oT[dt][2] * inv);
        o.w = f2bf(oT[dt][3] * inv);
        *(ushort4*)(yout + row * CDIM + h * 64 + 16 * dt + quad * 4) = o;
    }
}

// ---------------------------------------------------------------------------
extern "C" void kernel_launch(void* const* d_in, const int* in_sizes, int n_in,
                              void* d_out, int out_size, void* d_ws, size_t ws_size,
                              hipStream_t stream)
{
    const float* x      = (const float*)d_in[0];   // [2,2048,1024]
    const float* W_attn = (const float*)d_in[1];   // [1024,3072]
    const float* b_attn = (const float*)d_in[2];   // [3072]
    const float* W_proj = (const float*)d_in[3];   // [1024,1024]
    const float* b_proj = (const float*)d_in[4];   // [1024]
    float* out = (float*)d_out;                    // [2,2048,1024] fp32

    unsigned short* qkv = (unsigned short*)d_ws;             // bf16 [4096,3072] (V third unused)
    unsigned short* y   = qkv + (size_t)4096 * 3072;         // bf16 [4096,1024]
    unsigned short* xb  = y   + (size_t)4096 * 1024;         // bf16 [4096,1024]
    unsigned short* WtA = xb  + (size_t)4096 * 1024;         // bf16 [3072,1024]
    unsigned short* WtP = WtA + (size_t)3072 * 1024;         // bf16 [1024,1024]
    unsigned short* vT  = WtP + (size_t)1024 * 1024;         // bf16 [2048,2048]

    // 0) merged prepass: x->bf16, both weight transposes (one launch)
    prepass<<<dim3(6144), 256, 0, stream>>>(x, xb, W_attn, WtA, W_proj, WtP);

    // 1) qkv = bf16(x @ W_attn + b_attn); Q cols pre-scaled by 0.125*log2e;
    //    V cols (>=2048) transposed to vT
    gemm_bt<128, 128, true><<<dim3(3072 / 128, 4096 / 128), 256, 0, stream>>>(
        xb, WtA, b_attn, qkv, 4096, 3072, 1024, 2048, vT, 1024);

    // 2) flash attention -> y bf16 [4096,1024]  (QBLK=128, 512 threads)
    attn_mfma<<<dim3(BSZ * HNUM, TSEQ / 128), 512, 0, stream>>>(qkv, vT, y);

    // 3) out = y @ W_proj + b_proj (fp32)  M=4096 N=1024 K=1024, 64x64 tiles
    gemm_bt<64, 64, false><<<dim3(1024 / 64, 4096 / 64), 256, 0, stream>>>(
        y, WtP, b_proj, out, 4096, 1024, 1024, -1, nullptr, 0);
}

// Round 7
// 188.135 us; speedup vs baseline: 1.0209x; 1.0209x over previous
//
#include <hip/hip_runtime.h>
#include <math.h>

#define BSZ 2
#define TSEQ 2048
#define CDIM 1024
#define HNUM 16

typedef __attribute__((ext_vector_type(8))) short bhalf8;
typedef __attribute__((ext_vector_type(4))) short bhalf4;
typedef __attribute__((ext_vector_type(4))) float floatx4;

__device__ __forceinline__ unsigned short f2bf(float f) {
    union { float f; unsigned u; } v;
    v.f = f;
    unsigned r = v.u + 0x7FFFu + ((v.u >> 16) & 1u);
    return (unsigned short)(r >> 16);
}

__device__ __forceinline__ floatx4 fx4_zero() { floatx4 z = {0.f,0.f,0.f,0.f}; return z; }

// async global->LDS, 16 B per lane. lds dest = (wave-uniform base) + lane*16.
typedef __attribute__((address_space(3))) unsigned int lds_u32;
typedef const __attribute__((address_space(1))) unsigned int g_u32;
__device__ __forceinline__ void async_copy16(const void* g, void* l) {
    __builtin_amdgcn_global_load_lds((g_u32*)g, (lds_u32*)l, 16, 0, 0);
}

// ---------------------------------------------------------------------------
// Merged prepass (one launch):
//  blocks [0,2048):    x fp32 -> xb bf16 (8 elems/thread)
//  blocks [2048,5120): W_attn [1024,3072] -> WtA [3072,1024] bf16 transpose
//  blocks [5120,6144): W_proj [1024,1024] -> WtP [1024,1024] bf16 transpose
// ---------------------------------------------------------------------------
__device__ __forceinline__ void trans_tile(
    const float* __restrict__ W, unsigned short* __restrict__ Wt,
    int K, int N, int n0, int k0, int tid, float (*t)[33])
{
    const int tx = tid & 31, ty = tid >> 5;
#pragma unroll
    for (int i = 0; i < 4; ++i)
        t[ty + i * 8][tx] = W[(size_t)(k0 + ty + i * 8) * N + n0 + tx];
    __syncthreads();
#pragma unroll
    for (int i = 0; i < 4; ++i)
        Wt[(size_t)(n0 + ty + i * 8) * K + k0 + tx] = f2bf(t[tx][ty + i * 8]);
}

__global__ __launch_bounds__(256) void prepass(
    const float* __restrict__ x, unsigned short* __restrict__ xb,
    const float* __restrict__ Wa, unsigned short* __restrict__ WtA,
    const float* __restrict__ Wp, unsigned short* __restrict__ WtP)
{
    __shared__ float t[32][33];
    const int bid = blockIdx.x;
    const int tid = threadIdx.x;
    if (bid < 2048) {
        size_t i = ((size_t)bid * 256 + tid) * 8;
        float4 a = *(const float4*)(x + i);
        float4 b = *(const float4*)(x + i + 4);
        uint4 o;
        o.x = (unsigned)f2bf(a.x) | ((unsigned)f2bf(a.y) << 16);
        o.y = (unsigned)f2bf(a.z) | ((unsigned)f2bf(a.w) << 16);
        o.z = (unsigned)f2bf(b.x) | ((unsigned)f2bf(b.y) << 16);
        o.w = (unsigned)f2bf(b.z) | ((unsigned)f2bf(b.w) << 16);
        *(uint4*)(xb + i) = o;
    } else if (bid < 5120) {
        int tl = bid - 2048;                       // 96 n-tiles x 32 k-tiles
        trans_tile(Wa, WtA, 1024, 3072, (tl % 96) * 32, (tl / 96) * 32, tid, t);
    } else {
        int tl = bid - 5120;                       // 32 x 32
        trans_tile(Wp, WtP, 1024, 1024, (tl % 32) * 32, (tl / 32) * 32, tid, t);
    }
}

// ---------------------------------------------------------------------------
// bf16 MFMA GEMM (B^T input) + bias, single-barrier double-buffered K-loop.
// C[M,N] = A[M,K] @ Bt[N,K]^T + bias[N].  Block tile BM x BN, BK=32,
// 256 threads (4 waves). Wave covers (BM/2)x(BN/2); acc = MTxNT of 16x16.
// LDS chunk swizzle (T2): data (row r, k-chunk q) lives at slot
// c = (q + (r>>1)) & 3 of row r; staged via pre-swizzled GLOBAL source,
// read back with sw8 = ((quad + (col16>>1)) & 3) * 8 (conflict-free).
// Blocks whose colbase >= v_start write TRANSPOSED to vt via ushort4.
// Columns < q_end get scaled by 0.125*log2(e) in fp32 before bf16 round.
// ---------------------------------------------------------------------------
template<int BM, int BN, bool OUT_BF16>
__global__ __launch_bounds__(256) void gemm_bt(
    const unsigned short* __restrict__ A, const unsigned short* __restrict__ Bt,
    const float* __restrict__ bias, void* __restrict__ Cp,
    int M, int N, int K, int v_start, unsigned short* __restrict__ vt, int q_end)
{
    constexpr int ALINES = BM / 64;
    constexpr int BLINES = BN / 64;
    constexpr int MT = BM / 32;
    constexpr int NT = BN / 32;
    __shared__ unsigned short As[2][BM * 32];
    __shared__ unsigned short Bs[2][BN * 32];

    const int tid   = threadIdx.x;
    const int bm    = blockIdx.y;
    const int bn    = blockIdx.x;
    const int wave  = tid >> 6;
    const int col16 = tid & 15;
    const int quad  = (tid & 63) >> 4;
    const int wm    = (wave >> 1) * (BM / 2);
    const int wn    = (wave & 1) * (BN / 2);

    floatx4 acc[MT][NT];
#pragma unroll
    for (int i = 0; i < MT; ++i)
#pragma unroll
        for (int j = 0; j < NT; ++j) acc[i][j] = fx4_zero();

    // staging: lane covers row gr, global k-chunk pre-swizzled so that LDS
    // slot (gr, tid&3) holds chunk ((tid&3) - (gr>>1)) & 3
    const int gr = tid >> 2;
    const int gk = (((tid & 3) + 4 - ((tid >> 3) & 3)) & 3) * 8;
    const unsigned short* Ab = A  + (size_t)(bm * BM + gr) * K + gk;
    const unsigned short* Bb = Bt + (size_t)(bn * BN + gr) * K + gk;

    // fragment read: slot of k-chunk `quad` for row (.. + col16)
    const int sw8 = ((quad + (col16 >> 1)) & 3) * 8;

#define STAGE(k0, bf) { \
    char* AsB = (char*)As[bf] + wave * 1024; \
    char* BsB = (char*)Bs[bf] + wave * 1024; \
    _Pragma("unroll") \
    for (int l = 0; l < ALINES; ++l) \
        async_copy16(Ab + (size_t)l * 64 * K + (k0), AsB + l * 4096); \
    _Pragma("unroll") \
    for (int l = 0; l < BLINES; ++l) \
        async_copy16(Bb + (size_t)l * 64 * K + (k0), BsB + l * 4096); }

#define COMPUTE(bf) { \
    bhalf8 a[MT], b[NT]; \
    _Pragma("unroll") \
    for (int i = 0; i < MT; ++i) \
        a[i] = *(const bhalf8*)&As[bf][(wm + i * 16 + col16) * 32 + sw8]; \
    _Pragma("unroll") \
    for (int j = 0; j < NT; ++j) \
        b[j] = *(const bhalf8*)&Bs[bf][(wn + j * 16 + col16) * 32 + sw8]; \
    _Pragma("unroll") \
    for (int i = 0; i < MT; ++i) \
        _Pragma("unroll") \
        for (int j = 0; j < NT; ++j) \
            acc[i][j] = __builtin_amdgcn_mfma_f32_16x16x32_bf16(a[i], b[j], acc[i][j], 0, 0, 0); }

    STAGE(0, 0);
    __syncthreads();
    int buf = 0;
    for (int k0 = 0; k0 < K - 32; k0 += 32) {
        STAGE(k0 + 32, buf ^ 1);
        COMPUTE(buf);
        __syncthreads();
        buf ^= 1;
    }
    COMPUTE(buf);
#undef STAGE
#undef COMPUTE

    const int colbase = bn * BN + wn;
    const bool vpath = (v_start >= 0) && (colbase >= v_start);  // wave-uniform
    const float csc = (colbase < q_end) ? 0.18033688f : 1.0f;   // wave-uniform
#pragma unroll
    for (int j = 0; j < NT; ++j) {
        int col = colbase + j * 16 + col16;
        float bv = bias[col];
#pragma unroll
        for (int i = 0; i < MT; ++i) {
            if (vpath) {
                int row0 = bm * BM + wm + i * 16 + quad * 4;
                ushort4 o;
                o.x = f2bf((acc[i][j][0] + bv) * csc);
                o.y = f2bf((acc[i][j][1] + bv) * csc);
                o.z = f2bf((acc[i][j][2] + bv) * csc);
                o.w = f2bf((acc[i][j][3] + bv) * csc);
                size_t vrow = (size_t)((row0 >> 11) * 1024 + (col - v_start));
                *(ushort4*)(vt + vrow * 2048 + (row0 & 2047)) = o;
            } else {
#pragma unroll
                for (int r = 0; r < 4; ++r) {
                    int row = bm * BM + wm + i * 16 + quad * 4 + r;
                    float v = (acc[i][j][r] + bv) * csc;
                    if (OUT_BF16)
                        ((unsigned short*)Cp)[(size_t)row * N + col] = f2bf(v);
                    else
                        ((float*)Cp)[(size_t)row * N + col] = v;
                }
            }
        }
    }
}

// ---------------------------------------------------------------------------
// MFMA flash attention v8b: QBLK=128, 8 waves (512 thr), stride-76 V image.
// r6 post-mortem: v8's stride-64+XOR V layout put every V row at bank 0
// (128 B = exact bank wrap) -> 4-way ds_write conflicts, SQ_LDS_BANK_CONFLICT
// 131K -> 4.3M, attn 45->57 us.  v8b restores the r5-proven stride-76 image
// (row start bank = 6d mod 32; PV b64 read phase covers all 32 banks exactly
// once) inside the QBLK=128 structure.  This isolates the barrier-count
// hypothesis: tile-barriers per (b,h) 528->272, worst-CU path 80->48 tiles,
// per-wave staging halved (1 gload_lds + 1 V-uint4 per lane, was 2+2).
// Causality: wave w diag tile = 2qb + (w>>2); in-loop FULL (kb<wdiag) /
// DIAG (kb==wdiag); extra final tile kb=2qb+1 is DIAG for waves 4-7 only.
// K image (unchanged): row*128B + (chunk^(row&7))*16B, async-staged.
// LDS = 16KB K + 19KB V = 35840 B.
// ---------------------------------------------------------------------------
template<bool DIAG>
__device__ __forceinline__ void attn_tile(
    const unsigned short* __restrict__ Ks, const unsigned short* __restrict__ Vt,
    const bhalf8* qf, floatx4* oT, floatx4& accl,
    int col16, int quad, int qloc)
{
    const int sx = col16 & 7;
    const floatx4 minusC = {-17.31234049f, -17.31234049f, -17.31234049f, -17.31234049f};
    const bhalf4 ones = {0x3F80, 0x3F80, 0x3F80, 0x3F80};   // bf16 1.0 x4

    floatx4 s[4];
#pragma unroll
    for (int n = 0; n < 4; ++n) {
        const int row = 16 * n + col16;
        bhalf8 k0 = *(const bhalf8*)&Ks[row * 64 + ((quad ^ sx) * 8)];
        bhalf8 k1 = *(const bhalf8*)&Ks[row * 64 + (((4 + quad) ^ sx) * 8)];
        floatx4 t = __builtin_amdgcn_mfma_f32_16x16x32_bf16(k0, qf[0], minusC, 0, 0, 0);
        s[n] = __builtin_amdgcn_mfma_f32_16x16x32_bf16(k1, qf[1], t, 0, 0, 0);
    }

    bhalf4 pb[4];
#pragma unroll
    for (int n = 0; n < 4; ++n) {
        unsigned a[4];
#pragma unroll
        for (int r = 0; r < 4; ++r) {
            float p = exp2f(s[n][r]);
            if (DIAG) {
                if (16 * n + quad * 4 + r > qloc) p = 0.f;
            }
            a[r] = __float_as_uint(p) + 0x8000u;   // bias-round to bf16
        }
        union { unsigned u[2]; bhalf4 b; } uu;
        uu.u[0] = (a[0] >> 16) | (a[1] & 0xffff0000u);
        uu.u[1] = (a[2] >> 16) | (a[3] & 0xffff0000u);
        pb[n] = uu.b;
        // l-partial on the MFMA pipe: C[*][q] += sum_k P^T[k][q]
        accl = __builtin_amdgcn_mfma_f32_16x16x16bf16_1k(ones, pb[n], accl, 0, 0, 0);
    }

#pragma unroll
    for (int n = 0; n < 4; ++n) {
#pragma unroll
        for (int dt = 0; dt < 4; ++dt) {
            const int d = 16 * dt + col16;
            const bhalf4 av = *(const bhalf4*)&Vt[d * 76 + 16 * n + quad * 4];
            oT[dt] = __builtin_amdgcn_mfma_f32_16x16x16bf16_1k(av, pb[n], oT[dt], 0, 0, 0);
        }
    }
}

__global__ __launch_bounds__(512) void attn_mfma(
    const unsigned short* __restrict__ qkv,
    const unsigned short* __restrict__ vT,
    unsigned short* __restrict__ yout)
{
    __shared__ unsigned short Kbuf[2][64 * 64];
    __shared__ unsigned short Vbuf[2][64 * 76];

    const int tid   = threadIdx.x;
    const int wave  = tid >> 6;                               // 0..7
    const int col16 = tid & 15;
    const int quad  = (tid & 63) >> 4;
    const int qb    = (int)gridDim.y - 1 - (int)blockIdx.y;   // 0..15, longest first
    const int bh    = blockIdx.x;
    const int b     = bh >> 4;
    const int h     = bh & 15;

    const unsigned short* base  = qkv + (size_t)b * TSEQ * 3072 + h * 64;
    const unsigned short* kbase = base + CDIM;
    const unsigned short* vtb   = vT + (size_t)(b * 1024 + h * 64) * 2048;

    // Q fragments: lane holds Q[q=qb*128+wave*16+col16][d=quad*8+j]
    bhalf8 qf[2];
    {
        const unsigned short* qrow =
            base + (size_t)(qb * 128 + wave * 16 + col16) * 3072 + quad * 8;
        qf[0] = *(const bhalf8*)qrow;
        qf[1] = *(const bhalf8*)(qrow + 32);
    }

    // K staging: 512 lanes cover rows 0..63 (tid>>3), chunk (tid&7)^(row&7);
    // dest = Kbuf + wave*1024 + lane*16 reproduces exactly that (row,slot) map
    const int krow = tid >> 3;
    const int kchk = (tid & 7) ^ (krow & 7);
    const unsigned short* ksrc = kbase + (size_t)krow * 3072 + kchk * 8;

    // V staging: lane covers vT row d=tid>>3, t-chunk (tid&7)*8; stride-76 image
    const int vd  = tid >> 3;
    const int vt0 = (tid & 7) * 8;
    const int vsl = vd * 76 + vt0;
    const unsigned short* vsrc = vtb + (size_t)vd * 2048 + vt0;

#define KSTAGE(kb, bf) \
    async_copy16(ksrc + (size_t)(kb) * 64 * 3072, (char*)Kbuf[bf] + wave * 1024);

    floatx4 oT[4];
#pragma unroll
    for (int dt = 0; dt < 4; ++dt) oT[dt] = fx4_zero();
    floatx4 accl = fx4_zero();
    const int qloc  = (wave & 3) * 16 + col16;   // q row within its 64-row half
    const int wdiag = 2 * qb + (wave >> 2);      // this wave's diagonal tile

    {   // prologue: stage tile 0 into buf 0
        uint4 nv = *(const uint4*)vsrc;
        KSTAGE(0, 0);
        *(uint4*)&Vbuf[0][vsl] = nv;
    }
    __syncthreads();
    int buf = 0;
    const int last = 2 * qb + 1;
    for (int kb = 0; kb < last; ++kb) {
        uint4 nv = *(const uint4*)(vsrc + (size_t)(kb + 1) * 64);
        KSTAGE(kb + 1, buf ^ 1);
        if (kb < wdiag)
            attn_tile<false>(Kbuf[buf], Vbuf[buf], qf, oT, accl, col16, quad, qloc);
        else  // kb == wdiag (only waves 0-3 reach this in-loop)
            attn_tile<true>(Kbuf[buf], Vbuf[buf], qf, oT, accl, col16, quad, qloc);
        *(uint4*)&Vbuf[buf ^ 1][vsl] = nv;
        __syncthreads();
        buf ^= 1;
    }
    // final tile kb=last: DIAG for waves 4-7, skipped by waves 0-3
    if (wdiag == last)
        attn_tile<true>(Kbuf[buf], Vbuf[buf], qf, oT, accl, col16, quad, qloc);
#undef KSTAGE

    // epilogue: every lane holds the full l for its q; O^T/l, store
    const float inv = 1.0f / accl[0];
    const size_t row = (size_t)b * TSEQ + (size_t)qb * 128 + wave * 16 + col16;
#pragma unroll
    for (int dt = 0; dt < 4; ++dt) {
        ushort4 o;
        o.x = f2bf(oT[dt][0] * inv);
        o.y = f2bf(oT[dt][1] * inv);
        o.z = f2bf(oT[dt][2] * inv);
        o.w = f2bf(oT[dt][3] * inv);
        *(ushort4*)(yout + row * CDIM + h * 64 + 16 * dt + quad * 4) = o;
    }
}

// ---------------------------------------------------------------------------
extern "C" void kernel_launch(void* const* d_in, const int* in_sizes, int n_in,
                              void* d_out, int out_size, void* d_ws, size_t ws_size,
                              hipStream_t stream)
{
    const float* x      = (const float*)d_in[0];   // [2,2048,1024]
    const float* W_attn = (const float*)d_in[1];   // [1024,3072]
    const float* b_attn = (const float*)d_in[2];   // [3072]
    const float* W_proj = (const float*)d_in[3];   // [1024,1024]
    const float* b_proj = (const float*)d_in[4];   // [1024]
    float* out = (float*)d_out;                    // [2,2048,1024] fp32

    unsigned short* qkv = (unsigned short*)d_ws;             // bf16 [4096,3072] (V third unused)
    unsigned short* y   = qkv + (size_t)4096 * 3072;         // bf16 [4096,1024]
    unsigned short* xb  = y   + (size_t)4096 * 1024;         // bf16 [4096,1024]
    unsigned short* WtA = xb  + (size_t)4096 * 1024;         // bf16 [3072,1024]
    unsigned short* WtP = WtA + (size_t)3072 * 1024;         // bf16 [1024,1024]
    unsigned short* vT  = WtP + (size_t)1024 * 1024;         // bf16 [2048,2048]

    // 0) merged prepass: x->bf16, both weight transposes (one launch)
    prepass<<<dim3(6144), 256, 0, stream>>>(x, xb, W_attn, WtA, W_proj, WtP);

    // 1) qkv = bf16(x @ W_attn + b_attn); Q cols pre-scaled by 0.125*log2e;
    //    V cols (>=2048) transposed to vT
    gemm_bt<128, 128, true><<<dim3(3072 / 128, 4096 / 128), 256, 0, stream>>>(
        xb, WtA, b_attn, qkv, 4096, 3072, 1024, 2048, vT, 1024);

    // 2) flash attention -> y bf16 [4096,1024]  (QBLK=128, 512 threads)
    attn_mfma<<<dim3(BSZ * HNUM, TSEQ / 128), 512, 0, stream>>>(qkv, vT, y);

    // 3) out = y @ W_proj + b_proj (fp32)  M=4096 N=1024 K=1024, 64x64 tiles
    gemm_bt<64, 64, false><<<dim3(1024 / 64, 4096 / 64), 256, 0, stream>>>(
        y, WtP, b_proj, out, 4096, 1024, 1024, -1, nullptr, 0);
}